// Round 17
// baseline (301.868 us; speedup 1.0000x reference)
//
#include <hip/hip_runtime.h>
#include <hip/hip_bf16.h>

// Problem constants: B=16, D=64, T=256, BD=TD=H=128, H2=64, NRES=2
#define BDT_TOT 262144  // B*D*T

typedef __attribute__((ext_vector_type(8))) short bf16x8;
typedef __attribute__((ext_vector_type(4))) float f32x4;

__device__ __forceinline__ unsigned short f2b(float f) {
  __hip_bfloat16 h = __float2bfloat16(f);
  return *reinterpret_cast<unsigned short*>(&h);
}
__device__ __forceinline__ float bu2f(unsigned u16) {  // low 16 bits = bf16
  union { unsigned u; float f; } c;
  c.u = u16 << 16;
  return c.f;
}
// tanh-form gelu via v_exp/v_rcp (max abs dev from exact erf-gelu ~3e-4).
__device__ __forceinline__ float gelu_f(float x) {
  float x2 = x * x;
  float t = 1.5957691216057308f * x * fmaf(0.044715f, x2, 1.0f);
  return x * __builtin_amdgcn_rcpf(1.0f + __expf(-t));
}

// ---- async global->LDS, 16B/lane; LDS dest wave-uniform base (m104) ------
__device__ __forceinline__ void gl16(const unsigned char* g, unsigned char* l) {
  __builtin_amdgcn_global_load_lds((const __attribute__((address_space(1))) unsigned int*)g,
                                   (__attribute__((address_space(3))) unsigned int*)l, 16, 0, 0);
}

// Stage nkb KiB of a PRE-SWIZZLED global tile image into LDS (4 waves).
__device__ __forceinline__ void stage_gl(const unsigned char* __restrict__ g, unsigned char* l,
                                         int w, int lane, int nkb) {
  const int per = nkb >> 2;  // KiB per wave
  const unsigned char* gp = g + ((w * per) << 10) + (lane << 4);
  unsigned char* lp = l + ((w * per) << 10);
  for (int i = 0; i < per; ++i) gl16(gp + (i << 10), lp + (i << 10));
}

// ---- VALU staging (producers only): f32 rows -> swizzled bf16 tile -------
__device__ __forceinline__ void stage_f32(unsigned char* dst, const float* __restrict__ src,
                                          int ld, int tid, int nch, int nthr) {
  for (int c = tid; c < nch; c += nthr) {
    int row = c >> 4, kc = c & 15;
    const float* s = src + row * ld + kc * 8;
    float4 u = *(const float4*)(s);
    float4 v = *(const float4*)(s + 4);
    union { unsigned short h[8]; uint4 q; } pk;
    pk.h[0] = f2b(u.x); pk.h[1] = f2b(u.y); pk.h[2] = f2b(u.z); pk.h[3] = f2b(u.w);
    pk.h[4] = f2b(v.x); pk.h[5] = f2b(v.y); pk.h[6] = f2b(v.z); pk.h[7] = f2b(v.w);
    *(uint4*)(dst + row * 256 + ((kc * 16) ^ ((row & 7) << 4))) = pk.q;
  }
}

// ---- MFMA tile GEMMs (R1-verified fragment mapping) ----------------------
// D layout (16x16x32 bf16): col = lane&15, row = (lane>>4)*4 + r

// 128x128 tile, 8 waves: wm in {0,1}, wn in {0..3} (k_tmp)
__device__ __forceinline__ void gemm_tile(const unsigned char* Ar, const unsigned char* Br,
                                          int lane, int wm, int wn, f32x4 acc[4][2]) {
  const int lr = lane & 15, lk = lane >> 4;
#pragma unroll
  for (int ks = 0; ks < 4; ++ks) {
    const int kb = ks * 64 + lk * 16;
    bf16x8 a[4], bb[2];
#pragma unroll
    for (int mf = 0; mf < 4; ++mf) {
      int m = wm * 64 + mf * 16 + lr;
      a[mf] = *(const bf16x8*)(Ar + m * 256 + (kb ^ ((m & 7) << 4)));
    }
#pragma unroll
    for (int nf = 0; nf < 2; ++nf) {
      int n = wn * 32 + nf * 16 + lr;
      bb[nf] = *(const bf16x8*)(Br + n * 256 + (kb ^ ((n & 7) << 4)));
    }
#pragma unroll
    for (int mf = 0; mf < 4; ++mf)
#pragma unroll
      for (int nf = 0; nf < 2; ++nf)
        acc[mf][nf] = __builtin_amdgcn_mfma_f32_16x16x32_bf16(a[mf], bb[nf], acc[mf][nf], 0, 0, 0);
  }
}

// 64x128 tile, 4 waves: wave = wn in {0..3}, mf covers rows 0..63 (k_main)
__device__ __forceinline__ void gemm_tile64(const unsigned char* Ar, const unsigned char* Br,
                                            int lane, int wn, f32x4 acc[4][2]) {
  const int lr = lane & 15, lk = lane >> 4;
#pragma unroll
  for (int ks = 0; ks < 4; ++ks) {
    const int kb = ks * 64 + lk * 16;
    bf16x8 a[4], bb[2];
#pragma unroll
    for (int mf = 0; mf < 4; ++mf) {
      int m = mf * 16 + lr;
      a[mf] = *(const bf16x8*)(Ar + m * 256 + (kb ^ ((m & 7) << 4)));
    }
#pragma unroll
    for (int nf = 0; nf < 2; ++nf) {
      int n = wn * 32 + nf * 16 + lr;
      bb[nf] = *(const bf16x8*)(Br + n * 256 + (kb ^ ((n & 7) << 4)));
    }
#pragma unroll
    for (int mf = 0; mf < 4; ++mf)
#pragma unroll
      for (int nf = 0; nf < 2; ++nf)
        acc[mf][nf] = __builtin_amdgcn_mfma_f32_16x16x32_bf16(a[mf], bb[nf], acc[mf][nf], 0, 0, 0);
  }
}

__device__ __forceinline__ void zero_acc(f32x4 acc[4][2]) {
#pragma unroll
  for (int mf = 0; mf < 4; ++mf)
#pragma unroll
    for (int nf = 0; nf < 2; ++nf)
#pragma unroll
      for (int r = 0; r < 4; ++r) acc[mf][nf][r] = 0.0f;
}

// ---- rowwise linear: out[r][h] = sum_k in[r][k]*W[h][k] + b0[h]+b1[h]+b2[h]
__global__ __launch_bounds__(128) void rowlin_kernel(const float* __restrict__ in,
                                                     const float* __restrict__ W,
                                                     const float* __restrict__ b0,
                                                     const float* __restrict__ b1,
                                                     const float* __restrict__ b2,
                                                     float* __restrict__ out) {
  int r = blockIdx.x, h = threadIdx.x;
  __shared__ float xr[128];
  xr[h] = in[r * 128 + h];
  __syncthreads();
  const float* w = W + h * 128;
  float a = b0[h] + b1[h] + b2[h];
#pragma unroll 4
  for (int k = 0; k < 128; ++k) a = fmaf(xr[k], w[k], a);
  out[r * 128 + h] = a;
}

// ---- prep: blk0-4 weight tiles; blk5-36 trunk slabs -> SWIZZLED bf16 images
__global__ __launch_bounds__(256) void k_prep_cvt(
    const float* __restrict__ res_w1, const float* __restrict__ res_w2,
    const float* __restrict__ pos_w1, const float* __restrict__ ex_w1,
    const float* __restrict__ trunk,
    unsigned char* __restrict__ wTb, unsigned char* __restrict__ trunkb) {
  const int blk = blockIdx.x;
  const float* src; const float* src2 = nullptr; unsigned char* dst;
  if (blk == 0)      { src = res_w1;               dst = wTb; }
  else if (blk == 1) { src = res_w2;               dst = wTb + 32768; }
  else if (blk == 2) { src = res_w1 + 16384;       dst = wTb + 2 * 32768; }
  else if (blk == 3) { src = res_w2 + 16384;       dst = wTb + 3 * 32768; }
  else if (blk == 4) { src = pos_w1; src2 = ex_w1; dst = wTb + 4 * 32768; }
  else { src = trunk + (size_t)(blk - 5) * 16384; dst = trunkb + (size_t)(blk - 5) * 32768; }
  for (int c = threadIdx.x; c < 2048; c += 256) {
    const int row = c >> 4, kc = c & 15;
    const float* s = (src2 && row >= 64) ? (src2 + (row - 64) * 128 + kc * 8)
                                         : (src + row * 128 + kc * 8);
    float4 u = *(const float4*)s;
    float4 v = *(const float4*)(s + 4);
    union { unsigned short h[8]; uint4 q; } pk;
    pk.h[0]=f2b(u.x); pk.h[1]=f2b(u.y); pk.h[2]=f2b(u.z); pk.h[3]=f2b(u.w);
    pk.h[4]=f2b(v.x); pk.h[5]=f2b(v.y); pk.h[6]=f2b(v.z); pk.h[7]=f2b(v.w);
    *(uint4*)(dst + row * 256 + ((kc * 16) ^ ((row & 7) << 4))) = pk.q;
  }
}

// ---- k_tmp: tmp[bd] tile = branch @ W_bil[h] + W_tr, SWIZZLED global image
struct SMemTmp {
  unsigned char A[32768];   // be tile [m=bd][k=i] swz; reused as C staging (plain)
  unsigned char Bt[32768];  // W_bil[h]^T [n=j][k=i] swz
};

__global__ __launch_bounds__(512, 2) void k_tmp(const float* __restrict__ be,
                                                const float* __restrict__ Wb,
                                                const float* __restrict__ W_tr,
                                                unsigned char* __restrict__ tmpb) {
  __shared__ SMemTmp sm;
  const int h = blockIdx.x >> 3, bd0 = (blockIdx.x & 7) << 7;
  const int tid = threadIdx.x, lane = tid & 63, w = tid >> 6, wm = w >> 2, wn = w & 3;
  const int lr = lane & 15, lk = lane >> 4;

  stage_f32(sm.A, be + bd0 * 128, 128, tid, 2048, 512);
  {  // transpose-stage W_bil[h]: (i,j) -> Bt[j][i]
    const float* src = Wb + h * 16384;
    for (int it = tid; it < 4096; it += 512) {
      int i = it >> 5, j0 = (it & 31) * 4;
      float4 u = *(const float4*)(src + i * 128 + j0);
      float vv[4] = {u.x, u.y, u.z, u.w};
#pragma unroll
      for (int e = 0; e < 4; ++e) {
        int j = j0 + e;
        *(unsigned short*)(sm.Bt + j * 256 + ((2 * i) ^ ((j & 7) << 4))) = f2b(vv[e]);
      }
    }
  }
  __syncthreads();
  f32x4 acc[4][2];
  zero_acc(acc);
  gemm_tile(sm.A, sm.Bt, lane, wm, wn, acc);
  __syncthreads();  // all waves done reading sm.A -> safe to reuse as C staging
  float wtrv[2];
#pragma unroll
  for (int nf = 0; nf < 2; ++nf)
    wtrv[nf] = W_tr[h * 128 + wn * 32 + nf * 16 + lr];
#pragma unroll
  for (int mf = 0; mf < 4; ++mf)
#pragma unroll
    for (int nf = 0; nf < 2; ++nf)
#pragma unroll
      for (int r = 0; r < 4; ++r) {
        int row = wm * 64 + mf * 16 + lk * 4 + r;
        int col = wn * 32 + nf * 16 + lr;
        *(unsigned short*)(sm.A + row * 256 + col * 2) = f2b(acc[mf][nf][r] + wtrv[nf]);
      }
  __syncthreads();
  {  // copy-out as SWIZZLED image: tile (bd0+row), row h, swizzle (h&7)
    int row = tid >> 2, part = tid & 3;
    const uint4* s = (const uint4*)(sm.A + row * 256 + part * 64);
    unsigned char* gt = tmpb + (size_t)(bd0 + row) * 32768 + h * 256;
    const int hx = (h & 7) << 4;
#pragma unroll
    for (int e = 0; e < 4; ++e)
      *(uint4*)(gt + ((part * 64 + e * 16) ^ hx)) = s[e];
  }
}

// ---- main fused kernel: 256 thr / 4 waves, 64 t-rows x 128 h, 51 KB LDS --
struct SMemMain {
  unsigned char A[16384];   // fused / h1 (bf16 swz, 64 rows)
  unsigned char Bm[32768];  // current weight / tmp tile (bf16 swz, [n][k])
  float ssum[64 * 4];
  float ssq[64 * 4];
  float part[2][64][2];
};

// LayerNorm (64 rows): per-lane x[mf][nf][r] f32 -> bf16 into Adst AND packed xp.
__device__ __forceinline__ void ln_store64(float (&x)[4][2][4], unsigned (&xp)[4][4],
                                           float* ssum, float* ssq,
                                           int lane, int wn,
                                           const float* __restrict__ g, const float* __restrict__ be,
                                           unsigned char* Adst) {
  const int lr = lane & 15, lk = lane >> 4;
#pragma unroll
  for (int mf = 0; mf < 4; ++mf)
#pragma unroll
    for (int r = 0; r < 4; ++r) {
      float a = x[mf][0][r] + x[mf][1][r];
      float qq = x[mf][0][r] * x[mf][0][r] + x[mf][1][r] * x[mf][1][r];
#pragma unroll
      for (int m = 1; m < 16; m <<= 1) { a += __shfl_xor(a, m); qq += __shfl_xor(qq, m); }
      if (lr == 0) {
        int row = mf * 16 + lk * 4 + r;
        ssum[row * 4 + wn] = a;
        ssq[row * 4 + wn] = qq;
      }
    }
  __syncthreads();
  float gv[2], bv[2];
#pragma unroll
  for (int nf = 0; nf < 2; ++nf) {
    int col = wn * 32 + nf * 16 + lr;
    gv[nf] = g[col]; bv[nf] = be[col];
  }
#pragma unroll
  for (int mf = 0; mf < 4; ++mf)
#pragma unroll
    for (int r = 0; r < 4; ++r) {
      int row = mf * 16 + lk * 4 + r;
      float sum = ssum[row * 4 + 0] + ssum[row * 4 + 1] + ssum[row * 4 + 2] + ssum[row * 4 + 3];
      float sq  = ssq[row * 4 + 0] + ssq[row * 4 + 1] + ssq[row * 4 + 2] + ssq[row * 4 + 3];
      float mean = sum * 0.0078125f;
      float var  = sq * 0.0078125f - mean * mean;
      float rq = rsqrtf(var + 1e-5f);
      unsigned pk = 0;
#pragma unroll
      for (int nf = 0; nf < 2; ++nf) {
        int col = wn * 32 + nf * 16 + lr;
        float y = (x[mf][nf][r] - mean) * rq * gv[nf] + bv[nf];
        unsigned short us = f2b(y);
        pk |= ((unsigned)us) << (16 * nf);
        *(unsigned short*)(Adst + row * 256 + ((col * 2) ^ ((row & 7) << 4))) = us;
      }
      xp[mf][r] = pk;
    }
}

__global__ __launch_bounds__(256, 3) void k_main(
    const unsigned char* __restrict__ trunkb, const unsigned char* __restrict__ tmpb,
    const unsigned char* __restrict__ wTb,
    const float* __restrict__ br_all,
    const float* __restrict__ g_fn, const float* __restrict__ beta_fn,
    const float* __restrict__ res_b1, const float* __restrict__ res_b2,
    const float* __restrict__ res_g, const float* __restrict__ res_beta,
    const float* __restrict__ pos_b1, const float* __restrict__ pos_w2, const float* __restrict__ pos_b2,
    const float* __restrict__ ex_b1, const float* __restrict__ ex_w2, const float* __restrict__ ex_b2,
    const float* __restrict__ maskp, float* __restrict__ out) {
  __shared__ SMemMain sm;
  const int orig = blockIdx.x;
  const int gid = (orig & 7) * 512 + (orig >> 3);  // XCD swizzle, bijective (4096%8==0)
  const int bd = gid >> 2, qt = gid & 3;           // all 4 qt of a bd on one XCD
  const int b = bd >> 6, t0 = qt << 6;
  const int tid = threadIdx.x, lane = tid & 63, wn = tid >> 6;
  const int lr = lane & 15, lk = lane >> 4;

  // ---- G1: fused0 = trunk_qt @ (tmp[b,d]+W_tr)^T  (all gl-lds staging) ----
  stage_gl(trunkb + (size_t)(b * 256 + t0) * 256, sm.A, wn, lane, 16);
  stage_gl(tmpb + (size_t)bd * 32768, sm.Bm, wn, lane, 32);
  __syncthreads();                                       // bar 1 (vmcnt drained)
  f32x4 acc[4][2];
  zero_acc(acc);
  gemm_tile64(sm.A, sm.Bm, lane, wn, acc);

  // P0: x = acc + (b_bil+b_tr+b_br+branchproj)[h]
  unsigned xp[4][4];
  {
    float x[4][2][4];
#pragma unroll
    for (int nf = 0; nf < 2; ++nf) {
      int col = wn * 32 + nf * 16 + lr;
      float bb = br_all[bd * 128 + col];
#pragma unroll
      for (int mf = 0; mf < 4; ++mf)
#pragma unroll
        for (int r = 0; r < 4; ++r)
          x[mf][nf][r] = acc[mf][nf][r] + bb;
    }
    __syncthreads();  // all waves done with G1 reads of sm.A before LN overwrites it
    ln_store64(x, xp, sm.ssum, sm.ssq, lane, wn, g_fn, beta_fn, sm.A);  // stats bar inside
  }

  // ---- residual blocks ----
  for (int i = 0; i < 2; ++i) {
    stage_gl(wTb + (size_t)(i * 2) * 32768, sm.Bm, wn, lane, 32);  // res_w1[i]
    __syncthreads();                                     // bar: Bm staged + LN visible
    zero_acc(acc);
    gemm_tile64(sm.A, sm.Bm, lane, wn, acc);             // G2: fused @ w1[i]
    __syncthreads();                                     // bar: all done reading A
#pragma unroll
    for (int nf = 0; nf < 2; ++nf) {                     // h1 = gelu(D1+b1) -> sm.A
      int col = wn * 32 + nf * 16 + lr;
      float b1v = res_b1[i * 128 + col];
#pragma unroll
      for (int mf = 0; mf < 4; ++mf)
#pragma unroll
        for (int r = 0; r < 4; ++r) {
          int row = mf * 16 + lk * 4 + r;
          float hh = gelu_f(acc[mf][nf][r] + b1v);
          *(unsigned short*)(sm.A + row * 256 + ((col * 2) ^ ((row & 7) << 4))) = f2b(hh);
        }
    }
    stage_gl(wTb + (size_t)(i * 2 + 1) * 32768, sm.Bm, wn, lane, 32);  // res_w2[i]
    __syncthreads();                                     // bar: h1 + Bm staged
    zero_acc(acc);
    gemm_tile64(sm.A, sm.Bm, lane, wn, acc);             // G3: h1 @ w2[i]
    __syncthreads();                                     // bar: all done reading A
    {
      float x[4][2][4];
#pragma unroll
      for (int nf = 0; nf < 2; ++nf) {                   // residual from packed regs
        int col = wn * 32 + nf * 16 + lr;
        float b2v = res_b2[i * 128 + col];
#pragma unroll
        for (int mf = 0; mf < 4; ++mf)
#pragma unroll
          for (int r = 0; r < 4; ++r)
            x[mf][nf][r] = bu2f((xp[mf][r] >> (16 * nf)) & 0xffffu) + acc[mf][nf][r] + b2v;
      }
      ln_store64(x, xp, sm.ssum, sm.ssq, lane, wn,
                 res_g + i * 128, res_beta + i * 128, sm.A);
    }
  }

  // ---- heads: D = fused @ [pos_w1; ex_w1]^T ----
  stage_gl(wTb + (size_t)4 * 32768, sm.Bm, wn, lane, 32);
  __syncthreads();
  zero_acc(acc);
  gemm_tile64(sm.A, sm.Bm, lane, wn, acc);

  float s3[4][4];
#pragma unroll
  for (int mf = 0; mf < 4; ++mf)
#pragma unroll
    for (int r = 0; r < 4; ++r) s3[mf][r] = 0.0f;
#pragma unroll
  for (int nf = 0; nf < 2; ++nf) {
    int col = wn * 32 + nf * 16 + lr;
    float bias1 = (col < 64) ? pos_b1[col] : ex_b1[col - 64];
    float w2v = (col < 64) ? pos_w2[col] : ex_w2[col - 64];
#pragma unroll
    for (int mf = 0; mf < 4; ++mf)
#pragma unroll
      for (int r = 0; r < 4; ++r)
        s3[mf][r] += gelu_f(acc[mf][nf][r] + bias1) * w2v;
  }
#pragma unroll
  for (int mf = 0; mf < 4; ++mf)
#pragma unroll
    for (int r = 0; r < 4; ++r) {
      float a = s3[mf][r];
#pragma unroll
      for (int m = 1; m < 16; m <<= 1) a += __shfl_xor(a, m);
      s3[mf][r] = a;
    }
  if (lr == 0) {
#pragma unroll
    for (int mf = 0; mf < 4; ++mf)
#pragma unroll
      for (int r = 0; r < 4; ++r) {
        int row = mf * 16 + lk * 4 + r;
        sm.part[wn >> 1][row][wn & 1] = s3[mf][r];
      }
  }
  __syncthreads();
  if (tid < 128) {
    int row = tid >> 1, head = tid & 1;
    float v = sm.part[head][row][0] + sm.part[head][row][1];
    float mk = maskp[bd];
    int outr = bd * 256 + t0 + row;
    if (head == 0) {
      v += pos_b2[0];
      v = fminf(fmaxf(v, 0.0f), 1.0f);
      out[outr] = v * mk;
    } else {
      v += ex_b2[0];
      v = 1.0f / (1.0f + expf(-v));
      out[BDT_TOT + outr] = v * mk;
    }
  }
}

extern "C" void kernel_launch(void* const* d_in, const int* in_sizes, int n_in,
                              void* d_out, int out_size, void* d_ws, size_t ws_size,
                              hipStream_t stream) {
  const float* branch   = (const float*)d_in[0];
  const float* trunk    = (const float*)d_in[1];
  const float* mask     = (const float*)d_in[2];
  const float* W_bil    = (const float*)d_in[3];
  const float* b_bil    = (const float*)d_in[4];
  const float* W_br     = (const float*)d_in[5];
  const float* b_br     = (const float*)d_in[6];
  const float* W_tr     = (const float*)d_in[7];
  const float* b_tr     = (const float*)d_in[8];
  const float* g_fn     = (const float*)d_in[9];
  const float* beta_fn  = (const float*)d_in[10];
  const float* res_w1   = (const float*)d_in[11];
  const float* res_b1   = (const float*)d_in[12];
  const float* res_w2   = (const float*)d_in[13];
  const float* res_b2   = (const float*)d_in[14];
  const float* res_g    = (const float*)d_in[15];
  const float* res_beta = (const float*)d_in[16];
  const float* pos_w1   = (const float*)d_in[17];
  const float* pos_b1   = (const float*)d_in[18];
  const float* pos_w2   = (const float*)d_in[19];
  const float* pos_b2   = (const float*)d_in[20];
  const float* ex_w1    = (const float*)d_in[21];
  const float* ex_b1    = (const float*)d_in[22];
  const float* ex_w2    = (const float*)d_in[23];
  const float* ex_b2    = (const float*)d_in[24];
  float* out = (float*)d_out;

  // ws layout: 35.5 MB < proven 36.2 MB bound
  unsigned char* wsb = (unsigned char*)d_ws;
  unsigned char* tmpb   = wsb;                          // 33,554,432 B (swz images)
  float* br_all         = (float*)(wsb + 33554432);     //    524,288 B
  unsigned char* wTb    = wsb + 34078720;               //    163,840 B (swz images)
  unsigned char* trunkb = wsb + 34242560;               //  1,048,576 B (swz images)

  hipLaunchKernelGGL(k_prep_cvt, dim3(37), dim3(256), 0, stream,
                     res_w1, res_w2, pos_w1, ex_w1, trunk, wTb, trunkb);
  // br_all = branch @ W_br^T + (b_br + b_bil + b_tr)
  hipLaunchKernelGGL(rowlin_kernel, dim3(1024), dim3(128), 0, stream,
                     branch, W_br, b_br, b_bil, b_tr, br_all);
  hipLaunchKernelGGL(k_tmp, dim3(1024), dim3(512), 0, stream, branch, W_bil, W_tr, tmpb);
  hipLaunchKernelGGL(k_main, dim3(4096), dim3(256), 0, stream,
                     trunkb, tmpb, wTb, br_all, g_fn, beta_fn,
                     res_b1, res_b2, res_g, res_beta,
                     pos_b1, pos_w2, pos_b2, ex_b1, ex_w2, ex_b2,
                     mask, out);
}

// Round 18
// 284.112 us; speedup vs baseline: 1.0625x; 1.0625x over previous
//
#include <hip/hip_runtime.h>
#include <hip/hip_bf16.h>

// Problem constants: B=16, D=64, T=256, BD=TD=H=128, H2=64, NRES=2
#define BDT_TOT 262144  // B*D*T

typedef __attribute__((ext_vector_type(8))) short bf16x8;
typedef __attribute__((ext_vector_type(4))) float f32x4;

__device__ __forceinline__ unsigned short f2b(float f) {
  __hip_bfloat16 h = __float2bfloat16(f);
  return *reinterpret_cast<unsigned short*>(&h);
}
__device__ __forceinline__ float bu2f(unsigned u16) {  // low 16 bits = bf16
  union { unsigned u; float f; } c;
  c.u = u16 << 16;
  return c.f;
}
// tanh-form gelu via v_exp/v_rcp (max abs dev from exact erf-gelu ~3e-4).
__device__ __forceinline__ float gelu_f(float x) {
  float x2 = x * x;
  float t = 1.5957691216057308f * x * fmaf(0.044715f, x2, 1.0f);
  return x * __builtin_amdgcn_rcpf(1.0f + __expf(-t));
}

// ---- async global->LDS, 16B/lane; LDS dest wave-uniform base (m104) ------
__device__ __forceinline__ void gl16(const unsigned char* g, unsigned char* l) {
  __builtin_amdgcn_global_load_lds((const __attribute__((address_space(1))) unsigned int*)g,
                                   (__attribute__((address_space(3))) unsigned int*)l, 16, 0, 0);
}

// Stage nkb KiB of a PRE-SWIZZLED global tile image into LDS (4 waves).
__device__ __forceinline__ void stage_gl(const unsigned char* __restrict__ g, unsigned char* l,
                                         int w, int lane, int nkb) {
  const int per = nkb >> 2;  // KiB per wave
  const unsigned char* gp = g + ((w * per) << 10) + (lane << 4);
  unsigned char* lp = l + ((w * per) << 10);
  for (int i = 0; i < per; ++i) gl16(gp + (i << 10), lp + (i << 10));
}

// ---- VALU staging (producers only): f32 rows -> swizzled bf16 tile -------
__device__ __forceinline__ void stage_f32(unsigned char* dst, const float* __restrict__ src,
                                          int ld, int tid, int nch, int nthr) {
  for (int c = tid; c < nch; c += nthr) {
    int row = c >> 4, kc = c & 15;
    const float* s = src + row * ld + kc * 8;
    float4 u = *(const float4*)(s);
    float4 v = *(const float4*)(s + 4);
    union { unsigned short h[8]; uint4 q; } pk;
    pk.h[0] = f2b(u.x); pk.h[1] = f2b(u.y); pk.h[2] = f2b(u.z); pk.h[3] = f2b(u.w);
    pk.h[4] = f2b(v.x); pk.h[5] = f2b(v.y); pk.h[6] = f2b(v.z); pk.h[7] = f2b(v.w);
    *(uint4*)(dst + row * 256 + ((kc * 16) ^ ((row & 7) << 4))) = pk.q;
  }
}

// ---- MFMA tile GEMMs (R1-verified fragment mapping) ----------------------
// D layout (16x16x32 bf16): col = lane&15, row = (lane>>4)*4 + r

// 128x128 tile, 8 waves: wm in {0,1}, wn in {0..3} (k_tmp)
__device__ __forceinline__ void gemm_tile(const unsigned char* Ar, const unsigned char* Br,
                                          int lane, int wm, int wn, f32x4 acc[4][2]) {
  const int lr = lane & 15, lk = lane >> 4;
#pragma unroll
  for (int ks = 0; ks < 4; ++ks) {
    const int kb = ks * 64 + lk * 16;
    bf16x8 a[4], bb[2];
#pragma unroll
    for (int mf = 0; mf < 4; ++mf) {
      int m = wm * 64 + mf * 16 + lr;
      a[mf] = *(const bf16x8*)(Ar + m * 256 + (kb ^ ((m & 7) << 4)));
    }
#pragma unroll
    for (int nf = 0; nf < 2; ++nf) {
      int n = wn * 32 + nf * 16 + lr;
      bb[nf] = *(const bf16x8*)(Br + n * 256 + (kb ^ ((n & 7) << 4)));
    }
#pragma unroll
    for (int mf = 0; mf < 4; ++mf)
#pragma unroll
      for (int nf = 0; nf < 2; ++nf)
        acc[mf][nf] = __builtin_amdgcn_mfma_f32_16x16x32_bf16(a[mf], bb[nf], acc[mf][nf], 0, 0, 0);
  }
}

// 64x128 tile, 4 waves: wave = wn in {0..3}, mf covers rows 0..63 (k_main)
__device__ __forceinline__ void gemm_tile64(const unsigned char* Ar, const unsigned char* Br,
                                            int lane, int wn, f32x4 acc[4][2]) {
  const int lr = lane & 15, lk = lane >> 4;
#pragma unroll
  for (int ks = 0; ks < 4; ++ks) {
    const int kb = ks * 64 + lk * 16;
    bf16x8 a[4], bb[2];
#pragma unroll
    for (int mf = 0; mf < 4; ++mf) {
      int m = mf * 16 + lr;
      a[mf] = *(const bf16x8*)(Ar + m * 256 + (kb ^ ((m & 7) << 4)));
    }
#pragma unroll
    for (int nf = 0; nf < 2; ++nf) {
      int n = wn * 32 + nf * 16 + lr;
      bb[nf] = *(const bf16x8*)(Br + n * 256 + (kb ^ ((n & 7) << 4)));
    }
#pragma unroll
    for (int mf = 0; mf < 4; ++mf)
#pragma unroll
      for (int nf = 0; nf < 2; ++nf)
        acc[mf][nf] = __builtin_amdgcn_mfma_f32_16x16x32_bf16(a[mf], bb[nf], acc[mf][nf], 0, 0, 0);
  }
}

__device__ __forceinline__ void zero_acc(f32x4 acc[4][2]) {
#pragma unroll
  for (int mf = 0; mf < 4; ++mf)
#pragma unroll
    for (int nf = 0; nf < 2; ++nf)
#pragma unroll
      for (int r = 0; r < 4; ++r) acc[mf][nf][r] = 0.0f;
}

// ---- rowwise linear: out[r][h] = sum_k in[r][k]*W[h][k] + b0[h]+b1[h]+b2[h]
__global__ __launch_bounds__(128) void rowlin_kernel(const float* __restrict__ in,
                                                     const float* __restrict__ W,
                                                     const float* __restrict__ b0,
                                                     const float* __restrict__ b1,
                                                     const float* __restrict__ b2,
                                                     float* __restrict__ out) {
  int r = blockIdx.x, h = threadIdx.x;
  __shared__ float xr[128];
  xr[h] = in[r * 128 + h];
  __syncthreads();
  const float* w = W + h * 128;
  float a = b0[h] + b1[h] + b2[h];
#pragma unroll 4
  for (int k = 0; k < 128; ++k) a = fmaf(xr[k], w[k], a);
  out[r * 128 + h] = a;
}

// ---- prep: blk0-4 weight tiles; blk5-36 trunk slabs -> SWIZZLED bf16 images
__global__ __launch_bounds__(256) void k_prep_cvt(
    const float* __restrict__ res_w1, const float* __restrict__ res_w2,
    const float* __restrict__ pos_w1, const float* __restrict__ ex_w1,
    const float* __restrict__ trunk,
    unsigned char* __restrict__ wTb, unsigned char* __restrict__ trunkb) {
  const int blk = blockIdx.x;
  const float* src; const float* src2 = nullptr; unsigned char* dst;
  if (blk == 0)      { src = res_w1;               dst = wTb; }
  else if (blk == 1) { src = res_w2;               dst = wTb + 32768; }
  else if (blk == 2) { src = res_w1 + 16384;       dst = wTb + 2 * 32768; }
  else if (blk == 3) { src = res_w2 + 16384;       dst = wTb + 3 * 32768; }
  else if (blk == 4) { src = pos_w1; src2 = ex_w1; dst = wTb + 4 * 32768; }
  else { src = trunk + (size_t)(blk - 5) * 16384; dst = trunkb + (size_t)(blk - 5) * 32768; }
  for (int c = threadIdx.x; c < 2048; c += 256) {
    const int row = c >> 4, kc = c & 15;
    const float* s = (src2 && row >= 64) ? (src2 + (row - 64) * 128 + kc * 8)
                                         : (src + row * 128 + kc * 8);
    float4 u = *(const float4*)s;
    float4 v = *(const float4*)(s + 4);
    union { unsigned short h[8]; uint4 q; } pk;
    pk.h[0]=f2b(u.x); pk.h[1]=f2b(u.y); pk.h[2]=f2b(u.z); pk.h[3]=f2b(u.w);
    pk.h[4]=f2b(v.x); pk.h[5]=f2b(v.y); pk.h[6]=f2b(v.z); pk.h[7]=f2b(v.w);
    *(uint4*)(dst + row * 256 + ((kc * 16) ^ ((row & 7) << 4))) = pk.q;
  }
}

// ---- k_tmp: tmp[bd] tile = branch @ W_bil[h] + W_tr, SWIZZLED global image
struct SMemTmp {
  unsigned char A[32768];   // be tile [m=bd][k=i] swz; reused as C staging (plain)
  unsigned char Bt[32768];  // W_bil[h]^T [n=j][k=i] swz
};

__global__ __launch_bounds__(512, 2) void k_tmp(const float* __restrict__ be,
                                                const float* __restrict__ Wb,
                                                const float* __restrict__ W_tr,
                                                unsigned char* __restrict__ tmpb) {
  __shared__ SMemTmp sm;
  const int h = blockIdx.x >> 3, bd0 = (blockIdx.x & 7) << 7;
  const int tid = threadIdx.x, lane = tid & 63, w = tid >> 6, wm = w >> 2, wn = w & 3;
  const int lr = lane & 15, lk = lane >> 4;

  stage_f32(sm.A, be + bd0 * 128, 128, tid, 2048, 512);
  {  // transpose-stage W_bil[h]: (i,j) -> Bt[j][i]
    const float* src = Wb + h * 16384;
    for (int it = tid; it < 4096; it += 512) {
      int i = it >> 5, j0 = (it & 31) * 4;
      float4 u = *(const float4*)(src + i * 128 + j0);
      float vv[4] = {u.x, u.y, u.z, u.w};
#pragma unroll
      for (int e = 0; e < 4; ++e) {
        int j = j0 + e;
        *(unsigned short*)(sm.Bt + j * 256 + ((2 * i) ^ ((j & 7) << 4))) = f2b(vv[e]);
      }
    }
  }
  __syncthreads();
  f32x4 acc[4][2];
  zero_acc(acc);
  gemm_tile(sm.A, sm.Bt, lane, wm, wn, acc);
  __syncthreads();  // all waves done reading sm.A -> safe to reuse as C staging
  float wtrv[2];
#pragma unroll
  for (int nf = 0; nf < 2; ++nf)
    wtrv[nf] = W_tr[h * 128 + wn * 32 + nf * 16 + lr];
#pragma unroll
  for (int mf = 0; mf < 4; ++mf)
#pragma unroll
    for (int nf = 0; nf < 2; ++nf)
#pragma unroll
      for (int r = 0; r < 4; ++r) {
        int row = wm * 64 + mf * 16 + lk * 4 + r;
        int col = wn * 32 + nf * 16 + lr;
        *(unsigned short*)(sm.A + row * 256 + col * 2) = f2b(acc[mf][nf][r] + wtrv[nf]);
      }
  __syncthreads();
  {  // copy-out as SWIZZLED image: tile (bd0+row), row h, swizzle (h&7)
    int row = tid >> 2, part = tid & 3;
    const uint4* s = (const uint4*)(sm.A + row * 256 + part * 64);
    unsigned char* gt = tmpb + (size_t)(bd0 + row) * 32768 + h * 256;
    const int hx = (h & 7) << 4;
#pragma unroll
    for (int e = 0; e < 4; ++e)
      *(uint4*)(gt + ((part * 64 + e * 16) ^ hx)) = s[e];
  }
}

// ---- main fused kernel: 256 thr / 4 waves, 64 t-rows x 128 h, 51 KB LDS --
struct SMemMain {
  unsigned char A[16384];   // fused / h1 (bf16 swz, 64 rows)
  unsigned char Bm[32768];  // current weight / tmp tile (bf16 swz, [n][k])
  float ssum[64 * 4];
  float ssq[64 * 4];
  float part[2][64][2];
};

// LayerNorm (64 rows). After the internal stats barrier (at which point Bm is
// free and all prior vmcnt has drained), optionally ISSUE the next tile's
// gl-lds stage so its latency hides under the norm pass's VALU.
__device__ __forceinline__ void ln_store64(float (&x)[4][2][4], unsigned (&xp)[4][4],
                                           float* ssum, float* ssq,
                                           int lane, int wn,
                                           const float* __restrict__ g, const float* __restrict__ be,
                                           unsigned char* Adst,
                                           const unsigned char* stg_g, unsigned char* stg_l) {
  const int lr = lane & 15, lk = lane >> 4;
#pragma unroll
  for (int mf = 0; mf < 4; ++mf)
#pragma unroll
    for (int r = 0; r < 4; ++r) {
      float a = x[mf][0][r] + x[mf][1][r];
      float qq = x[mf][0][r] * x[mf][0][r] + x[mf][1][r] * x[mf][1][r];
#pragma unroll
      for (int m = 1; m < 16; m <<= 1) { a += __shfl_xor(a, m); qq += __shfl_xor(qq, m); }
      if (lr == 0) {
        int row = mf * 16 + lk * 4 + r;
        ssum[row * 4 + wn] = a;
        ssq[row * 4 + wn] = qq;
      }
    }
  __syncthreads();
  if (stg_g) stage_gl(stg_g, stg_l, wn, lane, 32);  // DMA overlaps norm pass below
  float gv[2], bv[2];
#pragma unroll
  for (int nf = 0; nf < 2; ++nf) {
    int col = wn * 32 + nf * 16 + lr;
    gv[nf] = g[col]; bv[nf] = be[col];
  }
#pragma unroll
  for (int mf = 0; mf < 4; ++mf)
#pragma unroll
    for (int r = 0; r < 4; ++r) {
      int row = mf * 16 + lk * 4 + r;
      float sum = ssum[row * 4 + 0] + ssum[row * 4 + 1] + ssum[row * 4 + 2] + ssum[row * 4 + 3];
      float sq  = ssq[row * 4 + 0] + ssq[row * 4 + 1] + ssq[row * 4 + 2] + ssq[row * 4 + 3];
      float mean = sum * 0.0078125f;
      float var  = sq * 0.0078125f - mean * mean;
      float rq = rsqrtf(var + 1e-5f);
      unsigned pk = 0;
#pragma unroll
      for (int nf = 0; nf < 2; ++nf) {
        int col = wn * 32 + nf * 16 + lr;
        float y = (x[mf][nf][r] - mean) * rq * gv[nf] + bv[nf];
        unsigned short us = f2b(y);
        pk |= ((unsigned)us) << (16 * nf);
        *(unsigned short*)(Adst + row * 256 + ((col * 2) ^ ((row & 7) << 4))) = us;
      }
      xp[mf][r] = pk;
    }
}

__global__ __launch_bounds__(256, 2) void k_main(
    const unsigned char* __restrict__ trunkb, const unsigned char* __restrict__ tmpb,
    const unsigned char* __restrict__ wTb,
    const float* __restrict__ br_all,
    const float* __restrict__ g_fn, const float* __restrict__ beta_fn,
    const float* __restrict__ res_b1, const float* __restrict__ res_b2,
    const float* __restrict__ res_g, const float* __restrict__ res_beta,
    const float* __restrict__ pos_b1, const float* __restrict__ pos_w2, const float* __restrict__ pos_b2,
    const float* __restrict__ ex_b1, const float* __restrict__ ex_w2, const float* __restrict__ ex_b2,
    const float* __restrict__ maskp, float* __restrict__ out) {
  __shared__ SMemMain sm;
  const int orig = blockIdx.x;
  const int gid = (orig & 7) * 512 + (orig >> 3);  // XCD swizzle, bijective (4096%8==0)
  const int bd = gid >> 2, qt = gid & 3;           // all 4 qt of a bd on one XCD
  const int b = bd >> 6, t0 = qt << 6;
  const int tid = threadIdx.x, lane = tid & 63, wn = tid >> 6;
  const int lr = lane & 15, lk = lane >> 4;

  // ---- G1: fused0 = trunk_qt @ (tmp[b,d]+W_tr)^T  (all gl-lds staging) ----
  stage_gl(trunkb + (size_t)(b * 256 + t0) * 256, sm.A, wn, lane, 16);
  stage_gl(tmpb + (size_t)bd * 32768, sm.Bm, wn, lane, 32);
  __syncthreads();                                       // bar 1 (vmcnt drained)
  f32x4 acc[4][2];
  zero_acc(acc);
  gemm_tile64(sm.A, sm.Bm, lane, wn, acc);

  // P0: x = acc + (b_bil+b_tr+b_br+branchproj)[h]
  unsigned xp[4][4];
  {
    float x[4][2][4];
#pragma unroll
    for (int nf = 0; nf < 2; ++nf) {
      int col = wn * 32 + nf * 16 + lr;
      float bb = br_all[bd * 128 + col];
#pragma unroll
      for (int mf = 0; mf < 4; ++mf)
#pragma unroll
        for (int r = 0; r < 4; ++r)
          x[mf][nf][r] = acc[mf][nf][r] + bb;
    }
    __syncthreads();  // all waves done with G1 reads of sm.A/Bm before LN overwrites A
    // ln stats bar -> issue w1[0] DMA -> norm pass overlaps it
    ln_store64(x, xp, sm.ssum, sm.ssq, lane, wn, g_fn, beta_fn, sm.A, wTb, sm.Bm);
  }
  __syncthreads();                                       // bar: Bm(w1[0]) + A(LN) ready

  // ---- residual blocks ----
  for (int i = 0; i < 2; ++i) {
    zero_acc(acc);
    gemm_tile64(sm.A, sm.Bm, lane, wn, acc);             // G2: fused @ w1[i]
    __syncthreads();                                     // bar: A & Bm reads done
    stage_gl(wTb + (size_t)(i * 2 + 1) * 32768, sm.Bm, wn, lane, 32);  // w2[i] DMA ...
#pragma unroll
    for (int nf = 0; nf < 2; ++nf) {                     // ... overlaps gelu epilogue
      int col = wn * 32 + nf * 16 + lr;
      float b1v = res_b1[i * 128 + col];
#pragma unroll
      for (int mf = 0; mf < 4; ++mf)
#pragma unroll
        for (int r = 0; r < 4; ++r) {
          int row = mf * 16 + lk * 4 + r;
          float hh = gelu_f(acc[mf][nf][r] + b1v);
          *(unsigned short*)(sm.A + row * 256 + ((col * 2) ^ ((row & 7) << 4))) = f2b(hh);
        }
    }
    __syncthreads();                                     // bar: h1 + Bm(w2[i]) ready
    zero_acc(acc);
    gemm_tile64(sm.A, sm.Bm, lane, wn, acc);             // G3: h1 @ w2[i]
    {
      float x[4][2][4];
#pragma unroll
      for (int nf = 0; nf < 2; ++nf) {                   // residual from packed regs
        int col = wn * 32 + nf * 16 + lr;
        float b2v = res_b2[i * 128 + col];
#pragma unroll
        for (int mf = 0; mf < 4; ++mf)
#pragma unroll
          for (int r = 0; r < 4; ++r)
            x[mf][nf][r] = bu2f((xp[mf][r] >> (16 * nf)) & 0xffffu) + acc[mf][nf][r] + b2v;
      }
      // stats bar (G3 reads of A/Bm done) -> issue next tile DMA -> norm overlaps
      ln_store64(x, xp, sm.ssum, sm.ssq, lane, wn,
                 res_g + i * 128, res_beta + i * 128, sm.A,
                 wTb + (size_t)(i == 0 ? 2 : 4) * 32768, sm.Bm);
    }
    __syncthreads();                                     // bar: Bm(next) + A(LN) ready
  }

  // ---- heads: D = fused @ [pos_w1; ex_w1]^T  (Bm already holds heads) ----
  zero_acc(acc);
  gemm_tile64(sm.A, sm.Bm, lane, wn, acc);

  float s3[4][4];
#pragma unroll
  for (int mf = 0; mf < 4; ++mf)
#pragma unroll
    for (int r = 0; r < 4; ++r) s3[mf][r] = 0.0f;
#pragma unroll
  for (int nf = 0; nf < 2; ++nf) {
    int col = wn * 32 + nf * 16 + lr;
    float bias1 = (col < 64) ? pos_b1[col] : ex_b1[col - 64];
    float w2v = (col < 64) ? pos_w2[col] : ex_w2[col - 64];
#pragma unroll
    for (int mf = 0; mf < 4; ++mf)
#pragma unroll
      for (int r = 0; r < 4; ++r)
        s3[mf][r] += gelu_f(acc[mf][nf][r] + bias1) * w2v;
  }
#pragma unroll
  for (int mf = 0; mf < 4; ++mf)
#pragma unroll
    for (int r = 0; r < 4; ++r) {
      float a = s3[mf][r];
#pragma unroll
      for (int m = 1; m < 16; m <<= 1) a += __shfl_xor(a, m);
      s3[mf][r] = a;
    }
  if (lr == 0) {
#pragma unroll
    for (int mf = 0; mf < 4; ++mf)
#pragma unroll
      for (int r = 0; r < 4; ++r) {
        int row = mf * 16 + lk * 4 + r;
        sm.part[wn >> 1][row][wn & 1] = s3[mf][r];
      }
  }
  __syncthreads();
  if (tid < 128) {
    int row = tid >> 1, head = tid & 1;
    float v = sm.part[head][row][0] + sm.part[head][row][1];
    float mk = maskp[bd];
    int outr = bd * 256 + t0 + row;
    if (head == 0) {
      v += pos_b2[0];
      v = fminf(fmaxf(v, 0.0f), 1.0f);
      out[outr] = v * mk;
    } else {
      v += ex_b2[0];
      v = 1.0f / (1.0f + expf(-v));
      out[BDT_TOT + outr] = v * mk;
    }
  }
}

extern "C" void kernel_launch(void* const* d_in, const int* in_sizes, int n_in,
                              void* d_out, int out_size, void* d_ws, size_t ws_size,
                              hipStream_t stream) {
  const float* branch   = (const float*)d_in[0];
  const float* trunk    = (const float*)d_in[1];
  const float* mask     = (const float*)d_in[2];
  const float* W_bil    = (const float*)d_in[3];
  const float* b_bil    = (const float*)d_in[4];
  const float* W_br     = (const float*)d_in[5];
  const float* b_br     = (const float*)d_in[6];
  const float* W_tr     = (const float*)d_in[7];
  const float* b_tr     = (const float*)d_in[8];
  const float* g_fn     = (const float*)d_in[9];
  const float* beta_fn  = (const float*)d_in[10];
  const float* res_w1   = (const float*)d_in[11];
  const float* res_b1   = (const float*)d_in[12];
  const float* res_w2   = (const float*)d_in[13];
  const float* res_b2   = (const float*)d_in[14];
  const float* res_g    = (const float*)d_in[15];
  const float* res_beta = (const float*)d_in[16];
  const float* pos_w1   = (const float*)d_in[17];
  const float* pos_b1   = (const float*)d_in[18];
  const float* pos_w2   = (const float*)d_in[19];
  const float* pos_b2   = (const float*)d_in[20];
  const float* ex_w1    = (const float*)d_in[21];
  const float* ex_b1    = (const float*)d_in[22];
  const float* ex_w2    = (const float*)d_in[23];
  const float* ex_b2    = (const float*)d_in[24];
  float* out = (float*)d_out;

  // ws layout: 35.5 MB < proven 36.2 MB bound
  unsigned char* wsb = (unsigned char*)d_ws;
  unsigned char* tmpb   = wsb;                          // 33,554,432 B (swz images)
  float* br_all         = (float*)(wsb + 33554432);     //    524,288 B
  unsigned char* wTb    = wsb + 34078720;               //    163,840 B (swz images)
  unsigned char* trunkb = wsb + 34242560;               //  1,048,576 B (swz images)

  hipLaunchKernelGGL(k_prep_cvt, dim3(37), dim3(256), 0, stream,
                     res_w1, res_w2, pos_w1, ex_w1, trunk, wTb, trunkb);
  // br_all = branch @ W_br^T + (b_br + b_bil + b_tr)
  hipLaunchKernelGGL(rowlin_kernel, dim3(1024), dim3(128), 0, stream,
                     branch, W_br, b_br, b_bil, b_tr, br_all);
  hipLaunchKernelGGL(k_tmp, dim3(1024), dim3(512), 0, stream, branch, W_bil, W_tr, tmpb);
  hipLaunchKernelGGL(k_main, dim3(4096), dim3(256), 0, stream,
                     trunkb, tmpb, wTb, br_all, g_fn, beta_fn,
                     res_b1, res_b2, res_g, res_beta,
                     pos_b1, pos_w2, pos_b2, ex_b1, ex_w2, ex_b2,
                     mask, out);
}

// Round 19
// 259.703 us; speedup vs baseline: 1.1624x; 1.0940x over previous
//
#include <hip/hip_runtime.h>
#include <hip/hip_bf16.h>

// Problem constants: B=16, D=64, T=256, BD=TD=H=128, H2=64, NRES=2
#define BDT_TOT 262144  // B*D*T

typedef __attribute__((ext_vector_type(8))) short bf16x8;
typedef __attribute__((ext_vector_type(4))) float f32x4;

__device__ __forceinline__ unsigned short f2b(float f) {
  __hip_bfloat16 h = __float2bfloat16(f);
  return *reinterpret_cast<unsigned short*>(&h);
}
__device__ __forceinline__ float bu2f(unsigned u16) {  // low 16 bits = bf16
  union { unsigned u; float f; } c;
  c.u = u16 << 16;
  return c.f;
}
// tanh-form gelu via v_exp/v_rcp (max abs dev from exact erf-gelu ~3e-4).
__device__ __forceinline__ float gelu_f(float x) {
  float x2 = x * x;
  float t = 1.5957691216057308f * x * fmaf(0.044715f, x2, 1.0f);
  return x * __builtin_amdgcn_rcpf(1.0f + __expf(-t));
}

// ---- async global->LDS, 16B/lane; LDS dest wave-uniform base (m104) ------
__device__ __forceinline__ void gl16(const unsigned char* g, unsigned char* l) {
  __builtin_amdgcn_global_load_lds((const __attribute__((address_space(1))) unsigned int*)g,
                                   (__attribute__((address_space(3))) unsigned int*)l, 16, 0, 0);
}

// Stage nkb KiB of a PRE-SWIZZLED global tile image into LDS (8 waves).
__device__ __forceinline__ void stage_gl8(const unsigned char* __restrict__ g, unsigned char* l,
                                          int w, int lane, int nkb) {
  const int per = nkb >> 3;  // KiB per wave (8 waves)
  const unsigned char* gp = g + ((w * per) << 10) + (lane << 4);
  unsigned char* lp = l + ((w * per) << 10);
  for (int i = 0; i < per; ++i) gl16(gp + (i << 10), lp + (i << 10));
}

// ---- VALU staging (producers only): f32 rows -> swizzled bf16 tile -------
__device__ __forceinline__ void stage_f32(unsigned char* dst, const float* __restrict__ src,
                                          int ld, int tid, int nch, int nthr) {
  for (int c = tid; c < nch; c += nthr) {
    int row = c >> 4, kc = c & 15;
    const float* s = src + row * ld + kc * 8;
    float4 u = *(const float4*)(s);
    float4 v = *(const float4*)(s + 4);
    union { unsigned short h[8]; uint4 q; } pk;
    pk.h[0] = f2b(u.x); pk.h[1] = f2b(u.y); pk.h[2] = f2b(u.z); pk.h[3] = f2b(u.w);
    pk.h[4] = f2b(v.x); pk.h[5] = f2b(v.y); pk.h[6] = f2b(v.z); pk.h[7] = f2b(v.w);
    *(uint4*)(dst + row * 256 + ((kc * 16) ^ ((row & 7) << 4))) = pk.q;
  }
}

// ---- MFMA tile GEMMs (R1-verified fragment mapping) ----------------------
// D layout (16x16x32 bf16): col = lane&15, row = (lane>>4)*4 + r

// 128x128 tile, 8 waves: wm in {0,1}, wn in {0..3} (k_tmp)
__device__ __forceinline__ void gemm_tile(const unsigned char* Ar, const unsigned char* Br,
                                          int lane, int wm, int wn, f32x4 acc[4][2]) {
  const int lr = lane & 15, lk = lane >> 4;
#pragma unroll
  for (int ks = 0; ks < 4; ++ks) {
    const int kb = ks * 64 + lk * 16;
    bf16x8 a[4], bb[2];
#pragma unroll
    for (int mf = 0; mf < 4; ++mf) {
      int m = wm * 64 + mf * 16 + lr;
      a[mf] = *(const bf16x8*)(Ar + m * 256 + (kb ^ ((m & 7) << 4)));
    }
#pragma unroll
    for (int nf = 0; nf < 2; ++nf) {
      int n = wn * 32 + nf * 16 + lr;
      bb[nf] = *(const bf16x8*)(Br + n * 256 + (kb ^ ((n & 7) << 4)));
    }
#pragma unroll
    for (int mf = 0; mf < 4; ++mf)
#pragma unroll
      for (int nf = 0; nf < 2; ++nf)
        acc[mf][nf] = __builtin_amdgcn_mfma_f32_16x16x32_bf16(a[mf], bb[nf], acc[mf][nf], 0, 0, 0);
  }
}

// 64x128 tile, 8 waves in 2x4 grid: wave (wm,wn) owns rows wm*32..+31,
// cols wn*32..+31. acc[2][2] (16 regs). (k_main)
__device__ __forceinline__ void gemm_tile32(const unsigned char* Ar, const unsigned char* Br,
                                            int lane, int wm, int wn, f32x4 acc[2][2]) {
  const int lr = lane & 15, lk = lane >> 4;
#pragma unroll
  for (int ks = 0; ks < 4; ++ks) {
    const int kb = ks * 64 + lk * 16;
    bf16x8 a[2], bb[2];
#pragma unroll
    for (int mf = 0; mf < 2; ++mf) {
      int m = wm * 32 + mf * 16 + lr;
      a[mf] = *(const bf16x8*)(Ar + m * 256 + (kb ^ ((m & 7) << 4)));
    }
#pragma unroll
    for (int nf = 0; nf < 2; ++nf) {
      int n = wn * 32 + nf * 16 + lr;
      bb[nf] = *(const bf16x8*)(Br + n * 256 + (kb ^ ((n & 7) << 4)));
    }
#pragma unroll
    for (int mf = 0; mf < 2; ++mf)
#pragma unroll
      for (int nf = 0; nf < 2; ++nf)
        acc[mf][nf] = __builtin_amdgcn_mfma_f32_16x16x32_bf16(a[mf], bb[nf], acc[mf][nf], 0, 0, 0);
  }
}

__device__ __forceinline__ void zero_acc8(f32x4 acc[4][2]) {
#pragma unroll
  for (int mf = 0; mf < 4; ++mf)
#pragma unroll
    for (int nf = 0; nf < 2; ++nf)
#pragma unroll
      for (int r = 0; r < 4; ++r) acc[mf][nf][r] = 0.0f;
}
__device__ __forceinline__ void zero_acc4(f32x4 acc[2][2]) {
#pragma unroll
  for (int mf = 0; mf < 2; ++mf)
#pragma unroll
    for (int nf = 0; nf < 2; ++nf)
#pragma unroll
      for (int r = 0; r < 4; ++r) acc[mf][nf][r] = 0.0f;
}

// ---- rowwise linear: out[r][h] = sum_k in[r][k]*W[h][k] + b0[h]+b1[h]+b2[h]
__global__ __launch_bounds__(128) void rowlin_kernel(const float* __restrict__ in,
                                                     const float* __restrict__ W,
                                                     const float* __restrict__ b0,
                                                     const float* __restrict__ b1,
                                                     const float* __restrict__ b2,
                                                     float* __restrict__ out) {
  int r = blockIdx.x, h = threadIdx.x;
  __shared__ float xr[128];
  xr[h] = in[r * 128 + h];
  __syncthreads();
  const float* w = W + h * 128;
  float a = b0[h] + b1[h] + b2[h];
#pragma unroll 4
  for (int k = 0; k < 128; ++k) a = fmaf(xr[k], w[k], a);
  out[r * 128 + h] = a;
}

// ---- prep: blk0-4 weight tiles; blk5-36 trunk slabs -> SWIZZLED bf16 images
__global__ __launch_bounds__(256) void k_prep_cvt(
    const float* __restrict__ res_w1, const float* __restrict__ res_w2,
    const float* __restrict__ pos_w1, const float* __restrict__ ex_w1,
    const float* __restrict__ trunk,
    unsigned char* __restrict__ wTb, unsigned char* __restrict__ trunkb) {
  const int blk = blockIdx.x;
  const float* src; const float* src2 = nullptr; unsigned char* dst;
  if (blk == 0)      { src = res_w1;               dst = wTb; }
  else if (blk == 1) { src = res_w2;               dst = wTb + 32768; }
  else if (blk == 2) { src = res_w1 + 16384;       dst = wTb + 2 * 32768; }
  else if (blk == 3) { src = res_w2 + 16384;       dst = wTb + 3 * 32768; }
  else if (blk == 4) { src = pos_w1; src2 = ex_w1; dst = wTb + 4 * 32768; }
  else { src = trunk + (size_t)(blk - 5) * 16384; dst = trunkb + (size_t)(blk - 5) * 32768; }
  for (int c = threadIdx.x; c < 2048; c += 256) {
    const int row = c >> 4, kc = c & 15;
    const float* s = (src2 && row >= 64) ? (src2 + (row - 64) * 128 + kc * 8)
                                         : (src + row * 128 + kc * 8);
    float4 u = *(const float4*)s;
    float4 v = *(const float4*)(s + 4);
    union { unsigned short h[8]; uint4 q; } pk;
    pk.h[0]=f2b(u.x); pk.h[1]=f2b(u.y); pk.h[2]=f2b(u.z); pk.h[3]=f2b(u.w);
    pk.h[4]=f2b(v.x); pk.h[5]=f2b(v.y); pk.h[6]=f2b(v.z); pk.h[7]=f2b(v.w);
    *(uint4*)(dst + row * 256 + ((kc * 16) ^ ((row & 7) << 4))) = pk.q;
  }
}

// ---- k_tmp: tmp[bd] tile = branch @ W_bil[h] + W_tr, SWIZZLED global image
struct SMemTmp {
  unsigned char A[32768];   // be tile [m=bd][k=i] swz; reused as C staging (plain)
  unsigned char Bt[32768];  // W_bil[h]^T [n=j][k=i] swz
};

__global__ __launch_bounds__(512, 2) void k_tmp(const float* __restrict__ be,
                                                const float* __restrict__ Wb,
                                                const float* __restrict__ W_tr,
                                                unsigned char* __restrict__ tmpb) {
  __shared__ SMemTmp sm;
  const int h = blockIdx.x >> 3, bd0 = (blockIdx.x & 7) << 7;
  const int tid = threadIdx.x, lane = tid & 63, w = tid >> 6, wm = w >> 2, wn = w & 3;
  const int lr = lane & 15, lk = lane >> 4;

  stage_f32(sm.A, be + bd0 * 128, 128, tid, 2048, 512);
  {  // transpose-stage W_bil[h]: (i,j) -> Bt[j][i]
    const float* src = Wb + h * 16384;
    for (int it = tid; it < 4096; it += 512) {
      int i = it >> 5, j0 = (it & 31) * 4;
      float4 u = *(const float4*)(src + i * 128 + j0);
      float vv[4] = {u.x, u.y, u.z, u.w};
#pragma unroll
      for (int e = 0; e < 4; ++e) {
        int j = j0 + e;
        *(unsigned short*)(sm.Bt + j * 256 + ((2 * i) ^ ((j & 7) << 4))) = f2b(vv[e]);
      }
    }
  }
  __syncthreads();
  f32x4 acc[4][2];
  zero_acc8(acc);
  gemm_tile(sm.A, sm.Bt, lane, wm, wn, acc);
  __syncthreads();  // all waves done reading sm.A -> safe to reuse as C staging
  float wtrv[2];
#pragma unroll
  for (int nf = 0; nf < 2; ++nf)
    wtrv[nf] = W_tr[h * 128 + wn * 32 + nf * 16 + lr];
#pragma unroll
  for (int mf = 0; mf < 4; ++mf)
#pragma unroll
    for (int nf = 0; nf < 2; ++nf)
#pragma unroll
      for (int r = 0; r < 4; ++r) {
        int row = wm * 64 + mf * 16 + lk * 4 + r;
        int col = wn * 32 + nf * 16 + lr;
        *(unsigned short*)(sm.A + row * 256 + col * 2) = f2b(acc[mf][nf][r] + wtrv[nf]);
      }
  __syncthreads();
  {  // copy-out as SWIZZLED image: tile (bd0+row), row h, swizzle (h&7)
    int row = tid >> 2, part = tid & 3;
    const uint4* s = (const uint4*)(sm.A + row * 256 + part * 64);
    unsigned char* gt = tmpb + (size_t)(bd0 + row) * 32768 + h * 256;
    const int hx = (h & 7) << 4;
#pragma unroll
    for (int e = 0; e < 4; ++e)
      *(uint4*)(gt + ((part * 64 + e * 16) ^ hx)) = s[e];
  }
}

// ---- main fused kernel: 512 thr / 8 waves (2x4), 64 t-rows x 128 h -------
struct SMemMain {
  unsigned char A[16384];   // fused / h1 (bf16 swz, 64 rows)
  unsigned char Bm[32768];  // current weight / tmp tile (bf16 swz, [n][k])
  float ssum[64 * 4];
  float ssq[64 * 4];
  float part[2][64][2];
};

// LayerNorm: wave (wm,wn) owns rows wm*32..+31 x cols wn*32..+31.
// Stats partials keyed by wn (4 per row); after the stats barrier optionally
// issue the next tile's gl-lds DMA (overlaps norm pass).
__device__ __forceinline__ void ln_store32(float (&x)[2][2][4], unsigned (&xp)[2][4],
                                           float* ssum, float* ssq,
                                           int lane, int wm, int wn,
                                           const float* __restrict__ g, const float* __restrict__ be,
                                           unsigned char* Adst,
                                           const unsigned char* stg_g, unsigned char* stg_l) {
  const int lr = lane & 15, lk = lane >> 4;
#pragma unroll
  for (int mf = 0; mf < 2; ++mf)
#pragma unroll
    for (int r = 0; r < 4; ++r) {
      float a = x[mf][0][r] + x[mf][1][r];
      float qq = x[mf][0][r] * x[mf][0][r] + x[mf][1][r] * x[mf][1][r];
#pragma unroll
      for (int m = 1; m < 16; m <<= 1) { a += __shfl_xor(a, m); qq += __shfl_xor(qq, m); }
      if (lr == 0) {
        int row = wm * 32 + mf * 16 + lk * 4 + r;
        ssum[row * 4 + wn] = a;
        ssq[row * 4 + wn] = qq;
      }
    }
  __syncthreads();
  if (stg_g) stage_gl8(stg_g, stg_l, wm * 4 + wn, lane, 32);  // DMA overlaps norm
  float gv[2], bv[2];
#pragma unroll
  for (int nf = 0; nf < 2; ++nf) {
    int col = wn * 32 + nf * 16 + lr;
    gv[nf] = g[col]; bv[nf] = be[col];
  }
#pragma unroll
  for (int mf = 0; mf < 2; ++mf)
#pragma unroll
    for (int r = 0; r < 4; ++r) {
      int row = wm * 32 + mf * 16 + lk * 4 + r;
      float sum = ssum[row * 4 + 0] + ssum[row * 4 + 1] + ssum[row * 4 + 2] + ssum[row * 4 + 3];
      float sq  = ssq[row * 4 + 0] + ssq[row * 4 + 1] + ssq[row * 4 + 2] + ssq[row * 4 + 3];
      float mean = sum * 0.0078125f;
      float var  = sq * 0.0078125f - mean * mean;
      float rq = rsqrtf(var + 1e-5f);
      unsigned pk = 0;
#pragma unroll
      for (int nf = 0; nf < 2; ++nf) {
        int col = wn * 32 + nf * 16 + lr;
        float y = (x[mf][nf][r] - mean) * rq * gv[nf] + bv[nf];
        unsigned short us = f2b(y);
        pk |= ((unsigned)us) << (16 * nf);
        *(unsigned short*)(Adst + row * 256 + ((col * 2) ^ ((row & 7) << 4))) = us;
      }
      xp[mf][r] = pk;
    }
}

__global__ __launch_bounds__(512, 4) void k_main(
    const unsigned char* __restrict__ trunkb, const unsigned char* __restrict__ tmpb,
    const unsigned char* __restrict__ wTb,
    const float* __restrict__ br_all,
    const float* __restrict__ g_fn, const float* __restrict__ beta_fn,
    const float* __restrict__ res_b1, const float* __restrict__ res_b2,
    const float* __restrict__ res_g, const float* __restrict__ res_beta,
    const float* __restrict__ pos_b1, const float* __restrict__ pos_w2, const float* __restrict__ pos_b2,
    const float* __restrict__ ex_b1, const float* __restrict__ ex_w2, const float* __restrict__ ex_b2,
    const float* __restrict__ maskp, float* __restrict__ out) {
  __shared__ SMemMain sm;
  const int orig = blockIdx.x;
  const int gid = (orig & 7) * 512 + (orig >> 3);  // XCD swizzle, bijective (4096%8==0)
  const int bd = gid >> 2, qt = gid & 3;           // all 4 qt of a bd on one XCD
  const int b = bd >> 6, t0 = qt << 6;
  const int tid = threadIdx.x, lane = tid & 63;
  const int w = tid >> 6, wm = w >> 2, wn = w & 3;  // 2x4 wave grid
  const int lr = lane & 15, lk = lane >> 4;

  // ---- G1: fused0 = trunk_qt @ (tmp[b,d]+W_tr)^T  (all gl-lds staging) ----
  stage_gl8(trunkb + (size_t)(b * 256 + t0) * 256, sm.A, w, lane, 16);
  stage_gl8(tmpb + (size_t)bd * 32768, sm.Bm, w, lane, 32);
  __syncthreads();                                       // bar 1 (vmcnt drained)
  f32x4 acc[2][2];
  zero_acc4(acc);
  gemm_tile32(sm.A, sm.Bm, lane, wm, wn, acc);

  // P0: x = acc + (b_bil+b_tr+b_br+branchproj)[h]
  unsigned xp[2][4];
  {
    float x[2][2][4];
#pragma unroll
    for (int nf = 0; nf < 2; ++nf) {
      int col = wn * 32 + nf * 16 + lr;
      float bb = br_all[bd * 128 + col];
#pragma unroll
      for (int mf = 0; mf < 2; ++mf)
#pragma unroll
        for (int r = 0; r < 4; ++r)
          x[mf][nf][r] = acc[mf][nf][r] + bb;
    }
    __syncthreads();  // all waves done with G1 reads of sm.A/Bm before LN overwrites A
    ln_store32(x, xp, sm.ssum, sm.ssq, lane, wm, wn, g_fn, beta_fn, sm.A, wTb, sm.Bm);
  }
  __syncthreads();                                       // bar: Bm(w1[0]) + A(LN) ready

  // ---- residual blocks ----
  for (int i = 0; i < 2; ++i) {
    zero_acc4(acc);
    gemm_tile32(sm.A, sm.Bm, lane, wm, wn, acc);         // G2: fused @ w1[i]
    __syncthreads();                                     // bar: A & Bm reads done
    stage_gl8(wTb + (size_t)(i * 2 + 1) * 32768, sm.Bm, w, lane, 32);  // w2[i] DMA ...
#pragma unroll
    for (int nf = 0; nf < 2; ++nf) {                     // ... overlaps gelu epilogue
      int col = wn * 32 + nf * 16 + lr;
      float b1v = res_b1[i * 128 + col];
#pragma unroll
      for (int mf = 0; mf < 2; ++mf)
#pragma unroll
        for (int r = 0; r < 4; ++r) {
          int row = wm * 32 + mf * 16 + lk * 4 + r;
          float hh = gelu_f(acc[mf][nf][r] + b1v);
          *(unsigned short*)(sm.A + row * 256 + ((col * 2) ^ ((row & 7) << 4))) = f2b(hh);
        }
    }
    __syncthreads();                                     // bar: h1 + Bm(w2[i]) ready
    zero_acc4(acc);
    gemm_tile32(sm.A, sm.Bm, lane, wm, wn, acc);         // G3: h1 @ w2[i]
    {
      float x[2][2][4];
#pragma unroll
      for (int nf = 0; nf < 2; ++nf) {                   // residual from packed regs
        int col = wn * 32 + nf * 16 + lr;
        float b2v = res_b2[i * 128 + col];
#pragma unroll
        for (int mf = 0; mf < 2; ++mf)
#pragma unroll
          for (int r = 0; r < 4; ++r)
            x[mf][nf][r] = bu2f((xp[mf][r] >> (16 * nf)) & 0xffffu) + acc[mf][nf][r] + b2v;
      }
      // stats bar (G3 reads of A/Bm done) -> issue next tile DMA -> norm overlaps
      ln_store32(x, xp, sm.ssum, sm.ssq, lane, wm, wn,
                 res_g + i * 128, res_beta + i * 128, sm.A,
                 wTb + (size_t)(i == 0 ? 2 : 4) * 32768, sm.Bm);
    }
    __syncthreads();                                     // bar: Bm(next) + A(LN) ready
  }

  // ---- heads: D = fused @ [pos_w1; ex_w1]^T  (Bm already holds heads) ----
  zero_acc4(acc);
  gemm_tile32(sm.A, sm.Bm, lane, wm, wn, acc);

  // cols 0-63 (wn 0,1) = pos head, cols 64-127 (wn 2,3) = ex head
  float s3[2][4];
#pragma unroll
  for (int mf = 0; mf < 2; ++mf)
#pragma unroll
    for (int r = 0; r < 4; ++r) s3[mf][r] = 0.0f;
#pragma unroll
  for (int nf = 0; nf < 2; ++nf) {
    int col = wn * 32 + nf * 16 + lr;
    float bias1 = (col < 64) ? pos_b1[col] : ex_b1[col - 64];
    float w2v = (col < 64) ? pos_w2[col] : ex_w2[col - 64];
#pragma unroll
    for (int mf = 0; mf < 2; ++mf)
#pragma unroll
      for (int r = 0; r < 4; ++r)
        s3[mf][r] += gelu_f(acc[mf][nf][r] + bias1) * w2v;
  }
#pragma unroll
  for (int mf = 0; mf < 2; ++mf)
#pragma unroll
    for (int r = 0; r < 4; ++r) {
      float a = s3[mf][r];
#pragma unroll
      for (int m = 1; m < 16; m <<= 1) a += __shfl_xor(a, m);
      s3[mf][r] = a;
    }
  if (lr == 0) {
#pragma unroll
    for (int mf = 0; mf < 2; ++mf)
#pragma unroll
      for (int r = 0; r < 4; ++r) {
        int row = wm * 32 + mf * 16 + lk * 4 + r;
        sm.part[wn >> 1][row][wn & 1] = s3[mf][r];
      }
  }
  __syncthreads();
  if (tid < 128) {
    int row = tid >> 1, head = tid & 1;
    float v = sm.part[head][row][0] + sm.part[head][row][1];
    float mk = maskp[bd];
    int outr = bd * 256 + t0 + row;
    if (head == 0) {
      v += pos_b2[0];
      v = fminf(fmaxf(v, 0.0f), 1.0f);
      out[outr] = v * mk;
    } else {
      v += ex_b2[0];
      v = 1.0f / (1.0f + expf(-v));
      out[BDT_TOT + outr] = v * mk;
    }
  }
}

extern "C" void kernel_launch(void* const* d_in, const int* in_sizes, int n_in,
                              void* d_out, int out_size, void* d_ws, size_t ws_size,
                              hipStream_t stream) {
  const float* branch   = (const float*)d_in[0];
  const float* trunk    = (const float*)d_in[1];
  const float* mask     = (const float*)d_in[2];
  const float* W_bil    = (const float*)d_in[3];
  const float* b_bil    = (const float*)d_in[4];
  const float* W_br     = (const float*)d_in[5];
  const float* b_br     = (const float*)d_in[6];
  const float* W_tr     = (const float*)d_in[7];
  const float* b_tr     = (const float*)d_in[8];
  const float* g_fn     = (const float*)d_in[9];
  const float* beta_fn  = (const float*)d_in[10];
  const float* res_w1   = (const float*)d_in[11];
  const float* res_b1   = (const float*)d_in[12];
  const float* res_w2   = (const float*)d_in[13];
  const float* res_b2   = (const float*)d_in[14];
  const float* res_g    = (const float*)d_in[15];
  const float* res_beta = (const float*)d_in[16];
  const float* pos_w1   = (const float*)d_in[17];
  const float* pos_b1   = (const float*)d_in[18];
  const float* pos_w2   = (const float*)d_in[19];
  const float* pos_b2   = (const float*)d_in[20];
  const float* ex_w1    = (const float*)d_in[21];
  const float* ex_b1    = (const float*)d_in[22];
  const float* ex_w2    = (const float*)d_in[23];
  const float* ex_b2    = (const float*)d_in[24];
  float* out = (float*)d_out;

  // ws layout: 35.5 MB < proven 36.2 MB bound
  unsigned char* wsb = (unsigned char*)d_ws;
  unsigned char* tmpb   = wsb;                          // 33,554,432 B (swz images)
  float* br_all         = (float*)(wsb + 33554432);     //    524,288 B
  unsigned char* wTb    = wsb + 34078720;               //    163,840 B (swz images)
  unsigned char* trunkb = wsb + 34242560;               //  1,048,576 B (swz images)

  hipLaunchKernelGGL(k_prep_cvt, dim3(37), dim3(256), 0, stream,
                     res_w1, res_w2, pos_w1, ex_w1, trunk, wTb, trunkb);
  // br_all = branch @ W_br^T + (b_br + b_bil + b_tr)
  hipLaunchKernelGGL(rowlin_kernel, dim3(1024), dim3(128), 0, stream,
                     branch, W_br, b_br, b_bil, b_tr, br_all);
  hipLaunchKernelGGL(k_tmp, dim3(1024), dim3(512), 0, stream, branch, W_bil, W_tr, tmpb);
  hipLaunchKernelGGL(k_main, dim3(4096), dim3(512), 0, stream,
                     trunkb, tmpb, wTb, br_all, g_fn, beta_fn,
                     res_b1, res_b2, res_g, res_beta,
                     pos_b1, pos_w2, pos_b2, ex_b1, ex_w2, ex_b2,
                     mask, out);
}